// Round 10
// baseline (157.057 us; speedup 1.0000x reference)
//
#include <hip/hip_runtime.h>
#include <hip/hip_bf16.h>
#include <math.h>

#define B_ 16
#define N_ 196
#define D_ 768
#define H_ 3072
#define C_ 10
#define MPAD 256                       // padded rows per batch for xb / h

typedef __attribute__((ext_vector_type(8))) short bf16x8;
typedef __attribute__((ext_vector_type(4))) float f32x4;

__device__ __forceinline__ ushort f2bu(float f) {
    union { float f; unsigned u; } c; c.f = f;
    unsigned u = c.u;
    unsigned r = (u + 0x7FFFu + ((u >> 16) & 1u)) >> 16;   // RNE f32->bf16
    return (ushort)r;
}

__device__ __forceinline__ void gl_lds16(const ushort* g, ushort* l) {
    __builtin_amdgcn_global_load_lds(
        (const __attribute__((address_space(1))) void*)g,
        (__attribute__((address_space(3))) void*)l, 16, 0, 0);
}

// ---------------- K0: x f32 -> bf16, padded rows (runs FIRST; tiny L3 footprint)
__global__ __launch_bounds__(256) void cvt_x(const float* __restrict__ x,
                                             ushort* __restrict__ xb) {
    const int i = blockIdx.x * 256 + threadIdx.x;       // [0, 301056)
    const int r = i / 96;                               // row in [0,3136)
    const int c8 = (i % 96) * 8;
    const int b = r / N_, nn = r - b * N_;
    const float4* src = reinterpret_cast<const float4*>(x + (long)r * D_ + c8);
    float4 a = src[0], bb = src[1];
    ushort t8[8] = { f2bu(a.x), f2bu(a.y), f2bu(a.z), f2bu(a.w),
                     f2bu(bb.x), f2bu(bb.y), f2bu(bb.z), f2bu(bb.w) };
    *reinterpret_cast<uint4*>(xb + ((long)b * MPAD + nn) * D_ + c8) =
        *reinterpret_cast<const uint4*>(t8);
}

// ---------------- K1: fg1 fused-mask GEMM, 128x128x64 (R7-proven, ~50 us when
// W1/m1 stay L3-resident — which the kernel ORDER now preserves).
__global__ __launch_bounds__(256) void fg1(
    const ushort* __restrict__ xb, const float* __restrict__ W1,
    const float* __restrict__ m1, const int* __restrict__ y,
    const float* __restrict__ b1, ushort* __restrict__ h)
{
    __shared__ ushort As[128][64];     // 16 KB, linear (gl_lds dest)
    __shared__ ushort Bs[128][72];     // 18.4 KB, padded
    const int ot = blockIdx.x;
    const int mt = blockIdx.y;
    const int b  = blockIdx.z;
    const int cls = y[b];
    const int tid = threadIdx.x, lane = tid & 63, wid = tid >> 6;
    const int wm = wid >> 1, wn = wid & 1;
    const int fr = lane & 15, fq = lane >> 4;
    const int lr = lane >> 3, le = (lane & 7) * 8;
    const int sr0 = tid >> 2, scb = (tid & 3) * 16;

    const ushort* Ab = xb + ((long)b * MPAD + mt * 128) * D_;
    const float*  Wb = W1 + (long)(ot * 128) * D_;
    const float*  Mb = m1 + ((long)cls * H_ + ot * 128) * D_;

    f32x4 acc[4][4] = {};
    #pragma unroll
    for (int t = 0; t < 12; ++t) {
        const int k0 = t * 64;
        // A: async global->LDS
        #pragma unroll
        for (int i = 0; i < 4; ++i) {
            const int r = wid * 32 + i * 8;
            gl_lds16(Ab + (long)(r + lr) * D_ + k0 + le, &As[r][0]);
        }
        // B: reg-stage W*mask f32 -> bf16 -> padded LDS (2 passes x 16 cols)
        #pragma unroll
        for (int p = 0; p < 2; ++p) {
            const int r = p * 64 + sr0;
            const float4* wp = reinterpret_cast<const float4*>(Wb + (long)r * D_ + k0 + scb);
            const float4* mp = reinterpret_cast<const float4*>(Mb + (long)r * D_ + k0 + scb);
            float4 w0 = wp[0], w1 = wp[1], w2v = wp[2], w3 = wp[3];
            float4 q0 = mp[0], q1 = mp[1], q2  = mp[2], q3 = mp[3];
            ushort ta[8] = { f2bu(w0.x*q0.x), f2bu(w0.y*q0.y), f2bu(w0.z*q0.z), f2bu(w0.w*q0.w),
                             f2bu(w1.x*q1.x), f2bu(w1.y*q1.y), f2bu(w1.z*q1.z), f2bu(w1.w*q1.w) };
            ushort tb[8] = { f2bu(w2v.x*q2.x), f2bu(w2v.y*q2.y), f2bu(w2v.z*q2.z), f2bu(w2v.w*q2.w),
                             f2bu(w3.x*q3.x), f2bu(w3.y*q3.y), f2bu(w3.z*q3.z), f2bu(w3.w*q3.w) };
            *reinterpret_cast<uint4*>(&Bs[r][scb])     = *reinterpret_cast<const uint4*>(ta);
            *reinterpret_cast<uint4*>(&Bs[r][scb + 8]) = *reinterpret_cast<const uint4*>(tb);
        }
        __syncthreads();
        #pragma unroll
        for (int kk = 0; kk < 64; kk += 32) {
            bf16x8 af[4], bf[4];
            #pragma unroll
            for (int i = 0; i < 4; ++i)
                af[i] = *reinterpret_cast<const bf16x8*>(&As[wm*64 + i*16 + fr][kk + fq*8]);
            #pragma unroll
            for (int j = 0; j < 4; ++j)
                bf[j] = *reinterpret_cast<const bf16x8*>(&Bs[wn*64 + j*16 + fr][kk + fq*8]);
            #pragma unroll
            for (int i = 0; i < 4; ++i)
                #pragma unroll
                for (int j = 0; j < 4; ++j)
                    acc[i][j] = __builtin_amdgcn_mfma_f32_16x16x32_bf16(af[i], bf[j], acc[i][j], 0, 0, 0);
        }
        __syncthreads();
    }
    #pragma unroll
    for (int j = 0; j < 4; ++j) {
        const int o = ot*128 + wn*64 + j*16 + fr;
        const float bias = b1[o];
        #pragma unroll
        for (int i = 0; i < 4; ++i) {
            #pragma unroll
            for (int e = 0; e < 4; ++e) {
                const int m = mt*128 + wm*64 + i*16 + fq*4 + e;
                float v = acc[i][j][e] + bias;
                v = 0.5f * v * (1.0f + erff(v * 0.70710678118654752f));
                h[((long)b * MPAD + m) * H_ + o] = f2bu(v);   // pad rows harmless
            }
        }
    }
}

// ---------------- K2: build wm2 bf16 (runs AFTER fg1 so its L3 thrash can't hurt fg1)
__global__ __launch_bounds__(256) void prep_wm2(
    const int* __restrict__ y, const float* __restrict__ W2,
    const float* __restrict__ m2, ushort* __restrict__ wm2)
{
    const int bid = blockIdx.x;                         // [0, 5760)
    const int tid = threadIdx.x;
    const int c = bid / 576, chunk = bid - c * 576;
    bool used = false;
    #pragma unroll
    for (int t = 0; t < B_; ++t) used |= (y[t] == c);
    if (!used) return;
    const long n = (long)H_ * D_;                       // 2,359,296
    const long i = (long)chunk * 4096 + tid * 16;
    const float4* wp = reinterpret_cast<const float4*>(W2 + i);
    const float4* mp = reinterpret_cast<const float4*>(m2 + c * n + i);
    float4 w0 = wp[0], w1 = wp[1], w2v = wp[2], w3 = wp[3];
    float4 q0 = mp[0], q1 = mp[1], q2  = mp[2], q3 = mp[3];
    ushort ta[8] = { f2bu(w0.x*q0.x), f2bu(w0.y*q0.y), f2bu(w0.z*q0.z), f2bu(w0.w*q0.w),
                     f2bu(w1.x*q1.x), f2bu(w1.y*q1.y), f2bu(w1.z*q1.z), f2bu(w1.w*q1.w) };
    ushort tb[8] = { f2bu(w2v.x*q2.x), f2bu(w2v.y*q2.y), f2bu(w2v.z*q2.z), f2bu(w2v.w*q2.w),
                     f2bu(w3.x*q3.x), f2bu(w3.y*q3.y), f2bu(w3.z*q3.z), f2bu(w3.w*q3.w) };
    uint4* op = reinterpret_cast<uint4*>(wm2 + c * n + i);
    op[0] = *reinterpret_cast<const uint4*>(ta);
    op[1] = *reinterpret_cast<const uint4*>(tb);
}

// ---------------- K3: mgemm2, bf16 both sides via gl_lds, 128x128x64, SK=4 (~20 us)
__global__ __launch_bounds__(256) void mgemm2(
    const ushort* __restrict__ h, const ushort* __restrict__ wm2,
    const int* __restrict__ y, float* __restrict__ part)
{
    __shared__ ushort As[128][64];
    __shared__ ushort Bs[128][64];
    const int ot = blockIdx.x;         // D tile 0..5
    const int mt = blockIdx.y;         // 0..1
    const int z  = blockIdx.z;         // 64
    const int b = z >> 2, sk = z & 3;
    const int cls = y[b];
    const int tid = threadIdx.x, lane = tid & 63, wid = tid >> 6;
    const int wm = wid >> 1, wn = wid & 1;
    const int fr = lane & 15, fq = lane >> 4;
    const int lr = lane >> 3, le = (lane & 7) * 8;

    const ushort* Ab = h + ((long)b * MPAD + mt * 128) * H_;
    const ushort* Bb = wm2 + (long)cls * ((long)H_ * D_) + (long)(ot * 128) * H_;

    f32x4 acc[4][4] = {};
    const int kt0 = sk * 12;
    #pragma unroll
    for (int t = 0; t < 12; ++t) {
        const int k0 = (kt0 + t) * 64;
        #pragma unroll
        for (int i = 0; i < 4; ++i) {
            const int r = wid * 32 + i * 8;
            gl_lds16(Ab + (long)(r + lr) * H_ + k0 + le, &As[r][0]);
        }
        #pragma unroll
        for (int i = 0; i < 4; ++i) {
            const int r = wid * 32 + i * 8;
            gl_lds16(Bb + (long)(r + lr) * H_ + k0 + le, &Bs[r][0]);
        }
        __syncthreads();
        #pragma unroll
        for (int kk = 0; kk < 64; kk += 32) {
            bf16x8 af[4], bf[4];
            #pragma unroll
            for (int i = 0; i < 4; ++i)
                af[i] = *reinterpret_cast<const bf16x8*>(&As[wm*64 + i*16 + fr][kk + fq*8]);
            #pragma unroll
            for (int j = 0; j < 4; ++j)
                bf[j] = *reinterpret_cast<const bf16x8*>(&Bs[wn*64 + j*16 + fr][kk + fq*8]);
            #pragma unroll
            for (int i = 0; i < 4; ++i)
                #pragma unroll
                for (int j = 0; j < 4; ++j)
                    acc[i][j] = __builtin_amdgcn_mfma_f32_16x16x32_bf16(af[i], bf[j], acc[i][j], 0, 0, 0);
        }
        __syncthreads();
    }
    float* op = part + (size_t)sk * (size_t)(B_ * N_ * D_);
    #pragma unroll
    for (int j = 0; j < 4; ++j) {
        const int o = ot*128 + wn*64 + j*16 + fr;
        #pragma unroll
        for (int i = 0; i < 4; ++i) {
            #pragma unroll
            for (int e = 0; e < 4; ++e) {
                const int m = mt*128 + wm*64 + i*16 + fq*4 + e;
                if (m < N_)
                    op[((long)b * N_ + m) * D_ + o] = acc[i][j][e];
            }
        }
    }
}

// ---------------- K4: out = sum_sk part[sk] + b2
__global__ __launch_bounds__(256) void reduce_k(const float* __restrict__ part,
                                                const float* __restrict__ b2,
                                                float* __restrict__ out, int SK)
{
    const int i = blockIdx.x * 256 + threadIdx.x;       // 602,112 float4s exactly
    const int stride4 = B_ * N_ * D_ / 4;
    float4 s = reinterpret_cast<const float4*>(part)[i];
    for (int k = 1; k < SK; ++k) {
        float4 p = reinterpret_cast<const float4*>(part)[(size_t)k * stride4 + i];
        s.x += p.x; s.y += p.y; s.z += p.z; s.w += p.w;
    }
    const int ob = (i % (D_ / 4)) * 4;
    float4 bias = *reinterpret_cast<const float4*>(b2 + ob);
    s.x += bias.x; s.y += bias.y; s.z += bias.z; s.w += bias.w;
    reinterpret_cast<float4*>(out)[i] = s;
}

// ================= fallback (R2 path, used only if ws too small) =================
__global__ __launch_bounds__(256) void fb_gemm1(
    const float* __restrict__ x, const int* __restrict__ y,
    const float* __restrict__ W1, const float* __restrict__ b1,
    const float* __restrict__ mask1, ushort* __restrict__ h)
{
    __shared__ ushort As[128][72];
    __shared__ ushort Bs[64][72];
    const int ot = blockIdx.x, mt = blockIdx.y, b = blockIdx.z;
    const int cls = y[b];
    const int tid = threadIdx.x, lane = tid & 63, wid = tid >> 6;
    const int wm = wid >> 1, wn = wid & 1;
    const int fr = lane & 15, fq = lane >> 4;
    const int sr = tid >> 2, sc = (tid & 3) * 16;
    f32x4 acc[4][2] = {};
    const long xbase = ((long)b * N_) * D_;
    const long wbase = (long)(ot * 64) * D_;
    const long mbase = ((long)cls * H_ + ot * 64) * D_;
    for (int kt = 0; kt < D_ / 64; ++kt) {
        const int k0 = kt * 64 + sc;
        #pragma unroll
        for (int half = 0; half < 2; ++half) {
            const int r = sr + half * 64;
            const int m = mt * 128 + r;
            ushort tmp[16];
            if (m < N_) {
                const float4* src = reinterpret_cast<const float4*>(x + xbase + (long)m * D_ + k0);
                #pragma unroll
                for (int j = 0; j < 4; ++j) {
                    float4 v = src[j];
                    tmp[4*j+0]=f2bu(v.x); tmp[4*j+1]=f2bu(v.y); tmp[4*j+2]=f2bu(v.z); tmp[4*j+3]=f2bu(v.w);
                }
            } else { for (int j = 0; j < 16; ++j) tmp[j] = 0; }
            *reinterpret_cast<uint4*>(&As[r][sc])   = *reinterpret_cast<const uint4*>(&tmp[0]);
            *reinterpret_cast<uint4*>(&As[r][sc+8]) = *reinterpret_cast<const uint4*>(&tmp[8]);
        }
        {
            const float4* wsrc = reinterpret_cast<const float4*>(W1 + wbase + (long)sr * D_ + k0);
            const float4* msrc = reinterpret_cast<const float4*>(mask1 + mbase + (long)sr * D_ + k0);
            ushort tmp[16];
            #pragma unroll
            for (int j = 0; j < 4; ++j) {
                float4 wv = wsrc[j], mv = msrc[j];
                tmp[4*j+0]=f2bu(wv.x*mv.x); tmp[4*j+1]=f2bu(wv.y*mv.y);
                tmp[4*j+2]=f2bu(wv.z*mv.z); tmp[4*j+3]=f2bu(wv.w*mv.w);
            }
            *reinterpret_cast<uint4*>(&Bs[sr][sc])   = *reinterpret_cast<const uint4*>(&tmp[0]);
            *reinterpret_cast<uint4*>(&Bs[sr][sc+8]) = *reinterpret_cast<const uint4*>(&tmp[8]);
        }
        __syncthreads();
        #pragma unroll
        for (int kk = 0; kk < 64; kk += 32) {
            bf16x8 af[4], bf[2];
            #pragma unroll
            for (int i = 0; i < 4; ++i) af[i] = *reinterpret_cast<const bf16x8*>(&As[wm*64+i*16+fr][kk+fq*8]);
            #pragma unroll
            for (int j = 0; j < 2; ++j) bf[j] = *reinterpret_cast<const bf16x8*>(&Bs[wn*32+j*16+fr][kk+fq*8]);
            #pragma unroll
            for (int i = 0; i < 4; ++i)
                #pragma unroll
                for (int j = 0; j < 2; ++j)
                    acc[i][j] = __builtin_amdgcn_mfma_f32_16x16x32_bf16(af[i], bf[j], acc[i][j], 0, 0, 0);
        }
        __syncthreads();
    }
    #pragma unroll
    for (int j = 0; j < 2; ++j) {
        const int o = ot*64 + wn*32 + j*16 + fr;
        const float bias = b1[o];
        #pragma unroll
        for (int i = 0; i < 4; ++i)
            #pragma unroll
            for (int e = 0; e < 4; ++e) {
                const int m = mt*128 + wm*64 + i*16 + fq*4 + e;
                if (m < N_) {
                    float v = acc[i][j][e] + bias;
                    v = 0.5f * v * (1.0f + erff(v * 0.70710678118654752f));
                    h[(((long)b * N_) + m) * H_ + o] = f2bu(v);
                }
            }
    }
}

__global__ __launch_bounds__(256) void fb_gemm2(
    const ushort* __restrict__ h, const int* __restrict__ y,
    const float* __restrict__ W2, const float* __restrict__ b2,
    const float* __restrict__ mask2, float* __restrict__ dst,
    int split, int nkt, int add_bias)
{
    __shared__ ushort As[128][72];
    __shared__ ushort Bs[64][72];
    const int ot = blockIdx.x, mt = blockIdx.y, z = blockIdx.z;
    const int b = z / split, sk = z - b * split;
    const int cls = y[b];
    const int tid = threadIdx.x, lane = tid & 63, wid = tid >> 6;
    const int wm = wid >> 1, wn = wid & 1;
    const int fr = lane & 15, fq = lane >> 4;
    const int sr = tid >> 2, sc = (tid & 3) * 16;
    f32x4 acc[4][2] = {};
    const long hbase = ((long)b * N_) * H_;
    const long wbase = (long)(ot * 64) * H_;
    const long mbase = ((long)cls * D_ + ot * 64) * H_;
    const int kt0 = sk * nkt;
    for (int kt = kt0; kt < kt0 + nkt; ++kt) {
        const int k0 = kt * 64 + sc;
        #pragma unroll
        for (int half = 0; half < 2; ++half) {
            const int r = sr + half * 64;
            const int m = mt * 128 + r;
            if (m < N_) {
                const uint4* src = reinterpret_cast<const uint4*>(h + hbase + (long)m * H_ + k0);
                *reinterpret_cast<uint4*>(&As[r][sc])   = src[0];
                *reinterpret_cast<uint4*>(&As[r][sc+8]) = src[1];
            } else {
                uint4 z4 = {0u,0u,0u,0u};
                *reinterpret_cast<uint4*>(&As[r][sc])   = z4;
                *reinterpret_cast<uint4*>(&As[r][sc+8]) = z4;
            }
        }
        {
            const float4* wsrc = reinterpret_cast<const float4*>(W2 + wbase + (long)sr * H_ + k0);
            const float4* msrc = reinterpret_cast<const float4*>(mask2 + mbase + (long)sr * H_ + k0);
            ushort tmp[16];
            #pragma unroll
            for (int j = 0; j < 4; ++j) {
                float4 wv = wsrc[j], mv = msrc[j];
                tmp[4*j+0]=f2bu(wv.x*mv.x); tmp[4*j+1]=f2bu(wv.y*mv.y);
                tmp[4*j+2]=f2bu(wv.z*mv.z); tmp[4*j+3]=f2bu(wv.w*mv.w);
            }
            *reinterpret_cast<uint4*>(&Bs[sr][sc])   = *reinterpret_cast<const uint4*>(&tmp[0]);
            *reinterpret_cast<uint4*>(&Bs[sr][sc+8]) = *reinterpret_cast<const uint4*>(&tmp[8]);
        }
        __syncthreads();
        #pragma unroll
        for (int kk = 0; kk < 64; kk += 32) {
            bf16x8 af[4], bf[2];
            #pragma unroll
            for (int i = 0; i < 4; ++i) af[i] = *reinterpret_cast<const bf16x8*>(&As[wm*64+i*16+fr][kk+fq*8]);
            #pragma unroll
            for (int j = 0; j < 2; ++j) bf[j] = *reinterpret_cast<const bf16x8*>(&Bs[wn*32+j*16+fr][kk+fq*8]);
            #pragma unroll
            for (int i = 0; i < 4; ++i)
                #pragma unroll
                for (int j = 0; j < 2; ++j)
                    acc[i][j] = __builtin_amdgcn_mfma_f32_16x16x32_bf16(af[i], bf[j], acc[i][j], 0, 0, 0);
        }
        __syncthreads();
    }
    float* op = dst + (size_t)sk * (size_t)(B_ * N_ * D_);
    #pragma unroll
    for (int j = 0; j < 2; ++j) {
        const int o = ot*64 + wn*32 + j*16 + fr;
        const float bias = add_bias ? b2[o] : 0.0f;
        #pragma unroll
        for (int i = 0; i < 4; ++i)
            #pragma unroll
            for (int e = 0; e < 4; ++e) {
                const int m = mt*128 + wm*64 + i*16 + fq*4 + e;
                if (m < N_) op[(((long)b * N_) + m) * D_ + o] = acc[i][j][e] + bias;
            }
    }
}

extern "C" void kernel_launch(void* const* d_in, const int* in_sizes, int n_in,
                              void* d_out, int out_size, void* d_ws, size_t ws_size,
                              hipStream_t stream) {
    const float* x  = (const float*)d_in[0];
    const int*   y  = (const int*)d_in[1];
    const float* W1 = (const float*)d_in[2];
    const float* b1 = (const float*)d_in[3];
    const float* W2 = (const float*)d_in[4];
    const float* b2 = (const float*)d_in[5];
    const float* m1 = (const float*)d_in[6];
    const float* m2 = (const float*)d_in[7];
    float* out = (float*)d_out;

    const size_t xbB  = (size_t)B_ * MPAD * D_ * 2;     //  6,291,456
    const size_t hB   = (size_t)B_ * MPAD * H_ * 2;     // 25,165,824
    const size_t oB   = (size_t)B_ * N_ * D_ * 4;       //  9,633,792
    const size_t wmB  = (size_t)C_ * H_ * D_ * 2;       // 47,185,920

    const size_t off_xb   = 0;
    const size_t off_h    = off_xb + xbB;
    const size_t off_part = off_h + hB;
    const size_t off_wm2  = off_part + 4 * oB;
    const size_t need     = off_wm2 + wmB;              // ~118 MB (ws ≈ 377 MB)

    if (ws_size >= need) {
        ushort* xb  = (ushort*)((char*)d_ws + off_xb);
        ushort* h   = (ushort*)((char*)d_ws + off_h);
        float* part = (float*)((char*)d_ws + off_part);
        ushort* wm2 = (ushort*)((char*)d_ws + off_wm2);

        // ORDER MATTERS: fg1 immediately after tiny cvt_x, so W1/m1 stay
        // L3-resident across replays (R7: ~50 us; R9 with prep first: 88 us).
        cvt_x<<<1176, 256, 0, stream>>>(x, xb);
        fg1<<<dim3(24, 2, 16), 256, 0, stream>>>(xb, W1, m1, y, b1, h);
        prep_wm2<<<5760, 256, 0, stream>>>(y, W2, m2, wm2);
        mgemm2<<<dim3(6, 2, 64), 256, 0, stream>>>(h, wm2, y, part);
        reduce_k<<<(B_ * N_ * D_ / 4) / 256, 256, 0, stream>>>(part, b2, out, 4);
    } else {
        // fallback: R2 path (unpadded h at ws base)
        const size_t fb_hB = (size_t)B_ * N_ * H_ * 2;
        ushort* h = (ushort*)d_ws;
        int SK = 0;
        if      (ws_size >= fb_hB + 4 * oB) SK = 4;
        else if (ws_size >= fb_hB + 2 * oB) SK = 2;
        float* part = (float*)((char*)d_ws + fb_hB);
        dim3 g1(H_ / 64, 2, B_);
        fb_gemm1<<<g1, 256, 0, stream>>>(x, y, W1, b1, m1, h);
        if (SK) {
            dim3 g2(D_ / 64, 2, B_ * SK);
            fb_gemm2<<<g2, 256, 0, stream>>>(h, y, W2, b2, m2, part, SK, 48 / SK, 0);
            reduce_k<<<(B_ * N_ * D_ / 4) / 256, 256, 0, stream>>>(part, b2, out, SK);
        } else {
            dim3 g2(D_ / 64, 2, B_);
            fb_gemm2<<<g2, 256, 0, stream>>>(h, y, W2, b2, m2, out, 1, 48, 1);
        }
    }
}

// Round 11
// 142.006 us; speedup vs baseline: 1.1060x; 1.1060x over previous
//
#include <hip/hip_runtime.h>
#include <hip/hip_bf16.h>
#include <math.h>

#define B_ 16
#define N_ 196
#define D_ 768
#define H_ 3072
#define C_ 10
#define MPAD 256                       // padded rows per batch for xb / h

typedef __attribute__((ext_vector_type(8))) short bf16x8;
typedef __attribute__((ext_vector_type(4))) float f32x4;

__device__ __forceinline__ ushort f2bu(float f) {
    union { float f; unsigned u; } c; c.f = f;
    unsigned u = c.u;
    unsigned r = (u + 0x7FFFu + ((u >> 16) & 1u)) >> 16;   // RNE f32->bf16
    return (ushort)r;
}

__device__ __forceinline__ void gl_lds16(const ushort* g, ushort* l) {
    __builtin_amdgcn_global_load_lds(
        (const __attribute__((address_space(1))) void*)g,
        (__attribute__((address_space(3))) void*)l, 16, 0, 0);
}

// ---------------- K0: ALL prep in one launch.
// blocks [0,1176): xb (x f32->bf16, padded rows)
// blocks [1176,6936): wm1 = bf16(W1*m1[c])   (576 blocks/class, 16 elems/thread)
// blocks [6936,12696): wm2 = bf16(W2*m2[c])  (LAST -> freshest in L3)
__global__ __launch_bounds__(256) void prep_all(
    const float* __restrict__ x, const int* __restrict__ y,
    const float* __restrict__ W1, const float* __restrict__ m1,
    const float* __restrict__ W2, const float* __restrict__ m2,
    ushort* __restrict__ xb, ushort* __restrict__ wm1, ushort* __restrict__ wm2)
{
    const int bid = blockIdx.x;
    const int tid = threadIdx.x;
    if (bid < 1176) {
        const int i = bid * 256 + tid;                  // [0, 301056)
        const int r = i / 96;                           // row in [0,3136)
        const int c8 = (i % 96) * 8;
        const int b = r / N_, nn = r - b * N_;
        const float4* src = reinterpret_cast<const float4*>(x + (long)r * D_ + c8);
        float4 a = src[0], bb = src[1];
        ushort t8[8] = { f2bu(a.x), f2bu(a.y), f2bu(a.z), f2bu(a.w),
                         f2bu(bb.x), f2bu(bb.y), f2bu(bb.z), f2bu(bb.w) };
        *reinterpret_cast<uint4*>(xb + ((long)b * MPAD + nn) * D_ + c8) =
            *reinterpret_cast<const uint4*>(t8);
        return;
    }
    const int v = bid - 1176;                           // [0, 11520)
    const int layer = v / 5760;
    const int w = v - layer * 5760;
    const int c = w / 576, chunk = w - c * 576;
    bool used = false;
    #pragma unroll
    for (int t = 0; t < B_; ++t) used |= (y[t] == c);
    if (!used) return;
    const float* W = layer ? W2 : W1;
    const float* M = layer ? m2 : m1;
    ushort*      O = layer ? wm2 : wm1;
    const long n = (long)H_ * D_;                       // 2,359,296
    const long i = (long)chunk * 4096 + tid * 16;
    const float4* wp = reinterpret_cast<const float4*>(W + i);
    const float4* mp = reinterpret_cast<const float4*>(M + c * n + i);
    float4 w0 = wp[0], w1 = wp[1], w2v = wp[2], w3 = wp[3];
    float4 q0 = mp[0], q1 = mp[1], q2  = mp[2], q3 = mp[3];
    ushort ta[8] = { f2bu(w0.x*q0.x), f2bu(w0.y*q0.y), f2bu(w0.z*q0.z), f2bu(w0.w*q0.w),
                     f2bu(w1.x*q1.x), f2bu(w1.y*q1.y), f2bu(w1.z*q1.z), f2bu(w1.w*q1.w) };
    ushort tb[8] = { f2bu(w2v.x*q2.x), f2bu(w2v.y*q2.y), f2bu(w2v.z*q2.z), f2bu(w2v.w*q2.w),
                     f2bu(w3.x*q3.x), f2bu(w3.y*q3.y), f2bu(w3.z*q3.z), f2bu(w3.w*q3.w) };
    uint4* op = reinterpret_cast<uint4*>(O + c * n + i);
    op[0] = *reinterpret_cast<const uint4*>(ta);
    op[1] = *reinterpret_cast<const uint4*>(tb);
}

// ---------------- shared GEMM core: 128x128x64, bf16 both sides via gl_lds.
// EPI=0: gemm1  A=xb[b][256][768],  B=wm1[cls][3072][768],  out h bf16 (+bias+gelu)
//         grid (24 ot, 2 mt, 16 b), 12 K-steps
// EPI=1: gemm2  A=h [b][256][3072], B=wm2[cls][768][3072], out f32 partial, SK=4
//         grid (6 ot, 2 mt, 64 z), 12 K-steps
template<int EPI>
__global__ __launch_bounds__(256) void mgemm(
    const ushort* __restrict__ A0, const ushort* __restrict__ Wm,
    const int* __restrict__ y, const float* __restrict__ bias1,
    ushort* __restrict__ hout, float* __restrict__ pout)
{
    constexpr int K = (EPI == 0) ? D_ : H_;
    __shared__ ushort As[128][64];
    __shared__ ushort Bs[128][64];
    const int ot = blockIdx.x;
    const int mt = blockIdx.y;
    const int z  = blockIdx.z;
    const int b  = (EPI == 0) ? z : (z >> 2);
    const int sk = (EPI == 0) ? 0 : (z & 3);
    const int cls = y[b];
    const int tid = threadIdx.x, lane = tid & 63, wid = tid >> 6;
    const int wm = wid >> 1, wn = wid & 1;
    const int fr = lane & 15, fq = lane >> 4;
    const int lr = lane >> 3, le = (lane & 7) * 8;

    const ushort* Ab = A0 + ((long)b * MPAD + mt * 128) * K;
    const ushort* Bb = Wm + (long)cls * ((long)H_ * D_) + (long)(ot * 128) * K;

    f32x4 acc[4][4] = {};
    const int kt0 = sk * 12;
    #pragma unroll
    for (int t = 0; t < 12; ++t) {
        const int k0 = (kt0 + t) * 64;
        #pragma unroll
        for (int i = 0; i < 4; ++i) {
            const int r = wid * 32 + i * 8;
            gl_lds16(Ab + (long)(r + lr) * K + k0 + le, &As[r][0]);
        }
        #pragma unroll
        for (int i = 0; i < 4; ++i) {
            const int r = wid * 32 + i * 8;
            gl_lds16(Bb + (long)(r + lr) * K + k0 + le, &Bs[r][0]);
        }
        __syncthreads();
        #pragma unroll
        for (int kk = 0; kk < 64; kk += 32) {
            bf16x8 af[4], bf[4];
            #pragma unroll
            for (int i = 0; i < 4; ++i)
                af[i] = *reinterpret_cast<const bf16x8*>(&As[wm*64 + i*16 + fr][kk + fq*8]);
            #pragma unroll
            for (int j = 0; j < 4; ++j)
                bf[j] = *reinterpret_cast<const bf16x8*>(&Bs[wn*64 + j*16 + fr][kk + fq*8]);
            #pragma unroll
            for (int i = 0; i < 4; ++i)
                #pragma unroll
                for (int j = 0; j < 4; ++j)
                    acc[i][j] = __builtin_amdgcn_mfma_f32_16x16x32_bf16(af[i], bf[j], acc[i][j], 0, 0, 0);
        }
        __syncthreads();
    }

    if (EPI == 0) {
        #pragma unroll
        for (int j = 0; j < 4; ++j) {
            const int o = ot*128 + wn*64 + j*16 + fr;
            const float bias = bias1[o];
            #pragma unroll
            for (int i = 0; i < 4; ++i) {
                #pragma unroll
                for (int e = 0; e < 4; ++e) {
                    const int m = mt*128 + wm*64 + i*16 + fq*4 + e;
                    float v = acc[i][j][e] + bias;
                    v = 0.5f * v * (1.0f + erff(v * 0.70710678118654752f));
                    hout[((long)b * MPAD + m) * H_ + o] = f2bu(v);   // pad rows harmless
                }
            }
        }
    } else {
        float* op = pout + (size_t)sk * (size_t)(B_ * N_ * D_);
        #pragma unroll
        for (int j = 0; j < 4; ++j) {
            const int o = ot*128 + wn*64 + j*16 + fr;
            #pragma unroll
            for (int i = 0; i < 4; ++i) {
                #pragma unroll
                for (int e = 0; e < 4; ++e) {
                    const int m = mt*128 + wm*64 + i*16 + fq*4 + e;
                    if (m < N_)
                        op[((long)b * N_ + m) * D_ + o] = acc[i][j][e];
                }
            }
        }
    }
}

// ---------------- K3: out = sum_sk part[sk] + b2
__global__ __launch_bounds__(256) void reduce_k(const float* __restrict__ part,
                                                const float* __restrict__ b2,
                                                float* __restrict__ out, int SK)
{
    const int i = blockIdx.x * 256 + threadIdx.x;       // 602,112 float4s exactly
    const int stride4 = B_ * N_ * D_ / 4;
    float4 s = reinterpret_cast<const float4*>(part)[i];
    for (int k = 1; k < SK; ++k) {
        float4 p = reinterpret_cast<const float4*>(part)[(size_t)k * stride4 + i];
        s.x += p.x; s.y += p.y; s.z += p.z; s.w += p.w;
    }
    const int ob = (i % (D_ / 4)) * 4;
    float4 bias = *reinterpret_cast<const float4*>(b2 + ob);
    s.x += bias.x; s.y += bias.y; s.z += bias.z; s.w += bias.w;
    reinterpret_cast<float4*>(out)[i] = s;
}

// ================= fallback (R2 path, used only if ws too small) =================
__global__ __launch_bounds__(256) void fb_gemm1(
    const float* __restrict__ x, const int* __restrict__ y,
    const float* __restrict__ W1, const float* __restrict__ b1,
    const float* __restrict__ mask1, ushort* __restrict__ h)
{
    __shared__ ushort As[128][72];
    __shared__ ushort Bs[64][72];
    const int ot = blockIdx.x, mt = blockIdx.y, b = blockIdx.z;
    const int cls = y[b];
    const int tid = threadIdx.x, lane = tid & 63, wid = tid >> 6;
    const int wm = wid >> 1, wn = wid & 1;
    const int fr = lane & 15, fq = lane >> 4;
    const int sr = tid >> 2, sc = (tid & 3) * 16;
    f32x4 acc[4][2] = {};
    const long xbase = ((long)b * N_) * D_;
    const long wbase = (long)(ot * 64) * D_;
    const long mbase = ((long)cls * H_ + ot * 64) * D_;
    for (int kt = 0; kt < D_ / 64; ++kt) {
        const int k0 = kt * 64 + sc;
        #pragma unroll
        for (int half = 0; half < 2; ++half) {
            const int r = sr + half * 64;
            const int m = mt * 128 + r;
            ushort tmp[16];
            if (m < N_) {
                const float4* src = reinterpret_cast<const float4*>(x + xbase + (long)m * D_ + k0);
                #pragma unroll
                for (int j = 0; j < 4; ++j) {
                    float4 v = src[j];
                    tmp[4*j+0]=f2bu(v.x); tmp[4*j+1]=f2bu(v.y); tmp[4*j+2]=f2bu(v.z); tmp[4*j+3]=f2bu(v.w);
                }
            } else { for (int j = 0; j < 16; ++j) tmp[j] = 0; }
            *reinterpret_cast<uint4*>(&As[r][sc])   = *reinterpret_cast<const uint4*>(&tmp[0]);
            *reinterpret_cast<uint4*>(&As[r][sc+8]) = *reinterpret_cast<const uint4*>(&tmp[8]);
        }
        {
            const float4* wsrc = reinterpret_cast<const float4*>(W1 + wbase + (long)sr * D_ + k0);
            const float4* msrc = reinterpret_cast<const float4*>(mask1 + mbase + (long)sr * D_ + k0);
            ushort tmp[16];
            #pragma unroll
            for (int j = 0; j < 4; ++j) {
                float4 wv = wsrc[j], mv = msrc[j];
                tmp[4*j+0]=f2bu(wv.x*mv.x); tmp[4*j+1]=f2bu(wv.y*mv.y);
                tmp[4*j+2]=f2bu(wv.z*mv.z); tmp[4*j+3]=f2bu(wv.w*mv.w);
            }
            *reinterpret_cast<uint4*>(&Bs[sr][sc])   = *reinterpret_cast<const uint4*>(&tmp[0]);
            *reinterpret_cast<uint4*>(&Bs[sr][sc+8]) = *reinterpret_cast<const uint4*>(&tmp[8]);
        }
        __syncthreads();
        #pragma unroll
        for (int kk = 0; kk < 64; kk += 32) {
            bf16x8 af[4], bf[2];
            #pragma unroll
            for (int i = 0; i < 4; ++i) af[i] = *reinterpret_cast<const bf16x8*>(&As[wm*64+i*16+fr][kk+fq*8]);
            #pragma unroll
            for (int j = 0; j < 2; ++j) bf[j] = *reinterpret_cast<const bf16x8*>(&Bs[wn*32+j*16+fr][kk+fq*8]);
            #pragma unroll
            for (int i = 0; i < 4; ++i)
                #pragma unroll
                for (int j = 0; j < 2; ++j)
                    acc[i][j] = __builtin_amdgcn_mfma_f32_16x16x32_bf16(af[i], bf[j], acc[i][j], 0, 0, 0);
        }
        __syncthreads();
    }
    #pragma unroll
    for (int j = 0; j < 2; ++j) {
        const int o = ot*64 + wn*32 + j*16 + fr;
        const float bias = b1[o];
        #pragma unroll
        for (int i = 0; i < 4; ++i)
            #pragma unroll
            for (int e = 0; e < 4; ++e) {
                const int m = mt*128 + wm*64 + i*16 + fq*4 + e;
                if (m < N_) {
                    float v = acc[i][j][e] + bias;
                    v = 0.5f * v * (1.0f + erff(v * 0.70710678118654752f));
                    h[(((long)b * N_) + m) * H_ + o] = f2bu(v);
                }
            }
    }
}

__global__ __launch_bounds__(256) void fb_gemm2(
    const ushort* __restrict__ h, const int* __restrict__ y,
    const float* __restrict__ W2, const float* __restrict__ b2,
    const float* __restrict__ mask2, float* __restrict__ dst,
    int split, int nkt, int add_bias)
{
    __shared__ ushort As[128][72];
    __shared__ ushort Bs[64][72];
    const int ot = blockIdx.x, mt = blockIdx.y, z = blockIdx.z;
    const int b = z / split, sk = z - b * split;
    const int cls = y[b];
    const int tid = threadIdx.x, lane = tid & 63, wid = tid >> 6;
    const int wm = wid >> 1, wn = wid & 1;
    const int fr = lane & 15, fq = lane >> 4;
    const int sr = tid >> 2, sc = (tid & 3) * 16;
    f32x4 acc[4][2] = {};
    const long hbase = ((long)b * N_) * H_;
    const long wbase = (long)(ot * 64) * H_;
    const long mbase = ((long)cls * D_ + ot * 64) * H_;
    const int kt0 = sk * nkt;
    for (int kt = kt0; kt < kt0 + nkt; ++kt) {
        const int k0 = kt * 64 + sc;
        #pragma unroll
        for (int half = 0; half < 2; ++half) {
            const int r = sr + half * 64;
            const int m = mt * 128 + r;
            if (m < N_) {
                const uint4* src = reinterpret_cast<const uint4*>(h + hbase + (long)m * H_ + k0);
                *reinterpret_cast<uint4*>(&As[r][sc])   = src[0];
                *reinterpret_cast<uint4*>(&As[r][sc+8]) = src[1];
            } else {
                uint4 z4 = {0u,0u,0u,0u};
                *reinterpret_cast<uint4*>(&As[r][sc])   = z4;
                *reinterpret_cast<uint4*>(&As[r][sc+8]) = z4;
            }
        }
        {
            const float4* wsrc = reinterpret_cast<const float4*>(W2 + wbase + (long)sr * H_ + k0);
            const float4* msrc = reinterpret_cast<const float4*>(mask2 + mbase + (long)sr * H_ + k0);
            ushort tmp[16];
            #pragma unroll
            for (int j = 0; j < 4; ++j) {
                float4 wv = wsrc[j], mv = msrc[j];
                tmp[4*j+0]=f2bu(wv.x*mv.x); tmp[4*j+1]=f2bu(wv.y*mv.y);
                tmp[4*j+2]=f2bu(wv.z*mv.z); tmp[4*j+3]=f2bu(wv.w*mv.w);
            }
            *reinterpret_cast<uint4*>(&Bs[sr][sc])   = *reinterpret_cast<const uint4*>(&tmp[0]);
            *reinterpret_cast<uint4*>(&Bs[sr][sc+8]) = *reinterpret_cast<const uint4*>(&tmp[8]);
        }
        __syncthreads();
        #pragma unroll
        for (int kk = 0; kk < 64; kk += 32) {
            bf16x8 af[4], bf[2];
            #pragma unroll
            for (int i = 0; i < 4; ++i) af[i] = *reinterpret_cast<const bf16x8*>(&As[wm*64+i*16+fr][kk+fq*8]);
            #pragma unroll
            for (int j = 0; j < 2; ++j) bf[j] = *reinterpret_cast<const bf16x8*>(&Bs[wn*32+j*16+fr][kk+fq*8]);
            #pragma unroll
            for (int i = 0; i < 4; ++i)
                #pragma unroll
                for (int j = 0; j < 2; ++j)
                    acc[i][j] = __builtin_amdgcn_mfma_f32_16x16x32_bf16(af[i], bf[j], acc[i][j], 0, 0, 0);
        }
        __syncthreads();
    }
    float* op = dst + (size_t)sk * (size_t)(B_ * N_ * D_);
    #pragma unroll
    for (int j = 0; j < 2; ++j) {
        const int o = ot*64 + wn*32 + j*16 + fr;
        const float bias = add_bias ? b2[o] : 0.0f;
        #pragma unroll
        for (int i = 0; i < 4; ++i)
            #pragma unroll
            for (int e = 0; e < 4; ++e) {
                const int m = mt*128 + wm*64 + i*16 + fq*4 + e;
                if (m < N_) op[(((long)b * N_) + m) * D_ + o] = acc[i][j][e] + bias;
            }
    }
}

extern "C" void kernel_launch(void* const* d_in, const int* in_sizes, int n_in,
                              void* d_out, int out_size, void* d_ws, size_t ws_size,
                              hipStream_t stream) {
    const float* x  = (const float*)d_in[0];
    const int*   y  = (const int*)d_in[1];
    const float* W1 = (const float*)d_in[2];
    const float* b1 = (const float*)d_in[3];
    const float* W2 = (const float*)d_in[4];
    const float* b2 = (const float*)d_in[5];
    const float* m1 = (const float*)d_in[6];
    const float* m2 = (const float*)d_in[7];
    float* out = (float*)d_out;

    const size_t xbB  = (size_t)B_ * MPAD * D_ * 2;     //  6,291,456
    const size_t hB   = (size_t)B_ * MPAD * H_ * 2;     // 25,165,824
    const size_t oB   = (size_t)B_ * N_ * D_ * 4;       //  9,633,792
    const size_t wmB  = (size_t)C_ * H_ * D_ * 2;       // 47,185,920

    const size_t off_xb   = 0;
    const size_t off_h    = off_xb + xbB;
    const size_t off_part = off_h + hB;
    const size_t off_wm1  = off_part + 4 * oB;
    const size_t off_wm2  = off_wm1 + wmB;
    const size_t need     = off_wm2 + wmB;              // ~164 MB (ws ≈ 377 MB)

    if (ws_size >= need) {
        ushort* xb  = (ushort*)((char*)d_ws + off_xb);
        ushort* h   = (ushort*)((char*)d_ws + off_h);
        float* part = (float*)((char*)d_ws + off_part);
        ushort* wm1 = (ushort*)((char*)d_ws + off_wm1);
        ushort* wm2 = (ushort*)((char*)d_ws + off_wm2);

        prep_all<<<12696, 256, 0, stream>>>(x, y, W1, m1, W2, m2, xb, wm1, wm2);
        mgemm<0><<<dim3(24, 2, 16), 256, 0, stream>>>(xb, wm1, y, b1, h, nullptr);
        mgemm<1><<<dim3(6, 2, 64), 256, 0, stream>>>(h, wm2, y, nullptr, nullptr, part);
        reduce_k<<<(B_ * N_ * D_ / 4) / 256, 256, 0, stream>>>(part, b2, out, 4);
    } else {
        // fallback: R2 path (unpadded h at ws base)
        const size_t fb_hB = (size_t)B_ * N_ * H_ * 2;
        ushort* h = (ushort*)d_ws;
        int SK = 0;
        if      (ws_size >= fb_hB + 4 * oB) SK = 4;
        else if (ws_size >= fb_hB + 2 * oB) SK = 2;
        float* part = (float*)((char*)d_ws + fb_hB);
        dim3 g1(H_ / 64, 2, B_);
        fb_gemm1<<<g1, 256, 0, stream>>>(x, y, W1, b1, m1, h);
        if (SK) {
            dim3 g2(D_ / 64, 2, B_ * SK);
            fb_gemm2<<<g2, 256, 0, stream>>>(h, y, W2, b2, m2, part, SK, 48 / SK, 0);
            reduce_k<<<(B_ * N_ * D_ / 4) / 256, 256, 0, stream>>>(part, b2, out, SK);
        } else {
            dim3 g2(D_ / 64, 2, B_);
            fb_gemm2<<<g2, 256, 0, stream>>>(h, y, W2, b2, m2, out, 1, 48, 1);
        }
    }
}